// Round 12
// baseline (246.269 us; speedup 1.0000x reference)
//
#include <hip/hip_runtime.h>
#include <math.h>

#define D 256
#define NX 16
#define L 2048
#define NBATCH 8
#define NTOK (NBATCH * L)
#define CL 32
#define NCH (L / CL)  // 64
#define LOG2E 1.44269504088896340736f

// ---------------- K0: At[n][d] = A[d][n]*LOG2E ; Wbct[d][c] = [WB;WC]^T -----
__global__ __launch_bounds__(256) void k0_prep(const float* __restrict__ A,
                                               const float* __restrict__ WB,
                                               const float* __restrict__ WC,
                                               float* __restrict__ At,
                                               float* __restrict__ Wbct) {
  int i = blockIdx.x * 256 + threadIdx.x;  // 12288 total
  if (i < 4096) {
    int d = i >> 4, n = i & 15;
    At[n * D + d] = A[i] * LOG2E;
  } else {
    int j = i - 4096;  // 8192
    int d = j >> 5, c = j & 31;
    Wbct[j] = (c < 16) ? WB[c * D + d] : WC[(c - 16) * D + d];
  }
}

// ---------------- K1a: front end + local chunk scan fused (unchanged) -------
__global__ __launch_bounds__(256) void k1a_front_scan(
    const float* __restrict__ y, const float* __restrict__ Win,
    const float* __restrict__ bin_, const float* __restrict__ ng,
    const float* __restrict__ nb, const float* __restrict__ Wbct,
    const float* __restrict__ qd, const float* __restrict__ pd,
    const float* __restrict__ At,
    float* __restrict__ hn, float* __restrict__ delta,
    float* __restrict__ Bm, float* __restrict__ Cm,
    float* __restrict__ muv, float* __restrict__ irsv,
    float* __restrict__ EX, float* __restrict__ T) {
  __shared__ float sy[32][32];
  __shared__ float sh[32][260];   // hn tile, pitch 260
  __shared__ float sB[32][NX];
  __shared__ float sdelta[32];
  int t = threadIdx.x;
  int tok0 = blockIdx.x * 32;
  {
    const float4* src = (const float4*)(y + (size_t)tok0 * 32);
    ((float4*)sy)[t] = src[t];
  }
  __syncthreads();
  int dcol = t & 63;
  int jrow = t >> 6;
  int d4 = dcol * 4;
  float4 bv = ((const float4*)bin_)[dcol];
  float4 acc[8];
  #pragma unroll
  for (int jj = 0; jj < 8; ++jj) acc[jj] = bv;
  const float4* Win4 = (const float4*)Win;
  #pragma unroll
  for (int k = 0; k < 32; ++k) {
    float4 wv = Win4[k * 64 + dcol];
    #pragma unroll
    for (int jj = 0; jj < 8; ++jj) {
      float av = sy[jrow * 8 + jj][k];
      acc[jj].x = fmaf(av, wv.x, acc[jj].x);
      acc[jj].y = fmaf(av, wv.y, acc[jj].y);
      acc[jj].z = fmaf(av, wv.z, acc[jj].z);
      acc[jj].w = fmaf(av, wv.w, acc[jj].w);
    }
  }
  float4 g4 = ((const float4*)ng)[dcol];
  float4 nb4 = ((const float4*)nb)[dcol];
  float4 q4 = ((const float4*)qd)[dcol];
  float pd0 = pd[0];
  #pragma unroll
  for (int jj = 0; jj < 8; ++jj) {
    int j = jrow * 8 + jj;
    int tok = tok0 + j;
    float4 a = acc[jj];
    float s1 = a.x + a.y + a.z + a.w;
    float s2 = a.x * a.x + a.y * a.y + a.z * a.z + a.w * a.w;
    #pragma unroll
    for (int off = 1; off < 64; off <<= 1) {
      s1 += __shfl_xor(s1, off);
      s2 += __shfl_xor(s2, off);
    }
    float mu = s1 * (1.f / D);
    float var = s2 * (1.f / D) - mu * mu;
    float rstd = rsqrtf(var + 1e-5f);
    if (dcol == 0) { muv[tok] = mu; irsv[tok] = sqrtf(var + 1e-5f); }
    float4 v4;
    v4.x = (a.x - mu) * rstd * g4.x + nb4.x;
    v4.y = (a.y - mu) * rstd * g4.y + nb4.y;
    v4.z = (a.z - mu) * rstd * g4.z + nb4.z;
    v4.w = (a.w - mu) * rstd * g4.w + nb4.w;
    ((float4*)(hn + (size_t)tok * D))[dcol] = v4;
    *(float4*)&sh[j][d4] = v4;
    float dd = v4.x * q4.x + v4.y * q4.y + v4.z * q4.z + v4.w * q4.w;
    #pragma unroll
    for (int off = 1; off < 64; off <<= 1) dd += __shfl_xor(dd, off);
    if (dcol == 0) {
      float xx = pd0 + dd;
      float dv = (xx > 20.f) ? xx : log1pf(expf(xx));
      delta[tok] = dv;
      sdelta[j] = dv;
    }
  }
  __syncthreads();
  if (t < 32) {
    float v = sdelta[t];
    #pragma unroll
    for (int off = 1; off < 32; off <<= 1) v += __shfl_xor(v, off);
    if (t == 0) T[blockIdx.x] = v;
  }
  // Phase C: [Bm|Cm] = sh @ Wbct
  int col4 = t & 7;
  int j = t >> 3;
  const float4* W4 = (const float4*)Wbct;
  float4 o = make_float4(0.f, 0.f, 0.f, 0.f);
  #pragma unroll 8
  for (int d = 0; d < 256; ++d) {
    float av = sh[j][d];
    float4 w = W4[d * 8 + col4];
    o.x = fmaf(av, w.x, o.x);
    o.y = fmaf(av, w.y, o.y);
    o.z = fmaf(av, w.z, o.z);
    o.w = fmaf(av, w.w, o.w);
  }
  int tokj = tok0 + j;
  if (col4 < 4) {
    ((float4*)(Bm + (size_t)tokj * NX))[col4] = o;
    *(float4*)&sB[j][col4 * 4] = o;
  } else {
    ((float4*)(Cm + (size_t)tokj * NX))[col4 - 4] = o;
  }
  __syncthreads();
  // local scan, zero init
  float a16[16];
  #pragma unroll
  for (int n = 0; n < 16; ++n) a16[n] = At[n * D + t];
  float x16[16];
  #pragma unroll
  for (int n = 0; n < 16; ++n) x16[n] = 0.f;
  for (int lo = 0; lo < CL; ++lo) {
    float dlt = sdelta[lo];
    float du = dlt * sh[lo][t];
    #pragma unroll
    for (int n = 0; n < 16; ++n)
      x16[n] = fmaf(exp2f(dlt * a16[n]), x16[n], du * sB[lo][n]);
  }
  size_t exbase = (size_t)blockIdx.x * (NX * D) + t;
  #pragma unroll
  for (int n = 0; n < 16; ++n) EX[exbase + n * D] = x16[n];
}

// ---------------- K2b: chunk-level scan (unchanged) -------------------------
__global__ __launch_bounds__(256) void k2b_chunkscan(
    const float* __restrict__ At, const float* __restrict__ T,
    float* __restrict__ EX) {
  __shared__ float sT[NCH];
  int b = blockIdx.x >> 4;
  int rem = ((blockIdx.x & 15) << 8) | threadIdx.x;  // n*D + d
  if (threadIdx.x < NCH) sT[threadIdx.x] = T[b * NCH + threadIdx.x];
  __syncthreads();
  float A2 = At[rem];
  size_t base = ((size_t)b << 18) + rem;
  float eq[4];
  #pragma unroll
  for (int j = 0; j < 4; ++j) eq[j] = EX[base + ((size_t)j << 12)];
  float x = 0.f;
  #pragma unroll 4
  for (int c = 0; c < NCH; ++c) {
    float e = eq[c & 3];
    if (c + 4 < NCH) eq[c & 3] = EX[base + ((size_t)(c + 4) << 12)];
    EX[base + ((size_t)c << 12)] = x;
    x = fmaf(exp2f(sT[c] * A2), x, e);
  }
}

__device__ __forceinline__ float gelu_exact(float x) {
  return 0.5f * x * (1.f + erff(x * 0.70710678118654752440f));
}

#define FMA4(AV, JJ)                          \
  acc[JJ].x = fmaf(AV, w.x, acc[JJ].x);       \
  acc[JJ].y = fmaf(AV, w.y, acc[JJ].y);       \
  acc[JJ].z = fmaf(AV, w.z, acc[JJ].z);       \
  acc[JJ].w = fmaf(AV, w.w, acc[JJ].w);

// ---------------- K2cd: scan + LN2 + MLP, transposed a-tile -----------------
// Scan (thread=d) writes aT[d][lo] (pitch 36, conflict-light). W1 loop reads
// a as 2 wave-uniform b128 per k. z reuses the aT region row-major (pitch 260).
__global__ __launch_bounds__(256) void k2cd_scan_mlp(
    const float* __restrict__ hn, const float* __restrict__ delta,
    const float* __restrict__ Bm, const float* __restrict__ Cm,
    const float* __restrict__ At, const float* __restrict__ EX,
    const float* __restrict__ muv, const float* __restrict__ irsv,
    const float* __restrict__ ng, const float* __restrict__ nb,
    const float* __restrict__ nfg, const float* __restrict__ nfb,
    const float* __restrict__ W1, const float* __restrict__ b1,
    const float* __restrict__ W2, const float* __restrict__ b2,
    float* __restrict__ out) {
  __shared__ float s_a[256 * 36];   // aT[d][tok] (36.9 KB); later z[32][260]
  __shared__ float s_w[32 * 256];   // W1 k-tiles, then W2 (32 KB)
  __shared__ float sB[32][NX];
  __shared__ float sC[32][NX];
  __shared__ float sdelta[32];
  __shared__ float smu[32];
  __shared__ float sirs[32];
  int t = threadIdx.x;
  int tok0 = blockIdx.x * 32;
  size_t tokbase = (size_t)tok0;
  if (t < 32) {
    sdelta[t] = delta[tokbase + t];
    smu[t] = muv[tokbase + t];
    sirs[t] = irsv[tokbase + t];
  }
  for (int i = t; i < 32 * NX; i += 256) {
    ((float*)sB)[i] = Bm[tokbase * NX + i];
    ((float*)sC)[i] = Cm[tokbase * NX + i];
  }
  float a16[16], x16[16];
  size_t exbase = (size_t)blockIdx.x * (NX * D) + t;
  #pragma unroll
  for (int n = 0; n < 16; ++n) {
    a16[n] = At[n * D + t];
    x16[n] = EX[exbase + n * D];
  }
  float nb_d = nb[t];
  float invg = 1.0f / ng[t];
  __syncthreads();
  // scan with true entering state; writes the TRANSPOSED activation tile
  for (int lo = 0; lo < CL; ++lo) {
    float hv = hn[(tokbase + lo) * D + t];
    float dlt = sdelta[lo];
    float du = dlt * hv;
    float p = 0.f;
    #pragma unroll
    for (int n = 0; n < 16; ++n) {
      x16[n] = fmaf(exp2f(dlt * a16[n]), x16[n], du * sB[lo][n]);
      p = fmaf(x16[n], sC[lo][n], p);
    }
    float h = fmaf((hv - nb_d) * invg, sirs[lo], smu[lo]);
    s_a[t * 36 + lo] = h + p;  // aT row t: conflict-light scalar write
  }
  __syncthreads();
  // LN2 over columns of aT: wave jrow handles tokens j8..j8+7; lane owns
  // d = dcol, dcol+64, dcol+128, dcol+192
  int dcol = t & 63, jrow = t >> 6;
  int d4 = dcol * 4, j8 = jrow * 8;
  {
    float g0 = nfg[dcol], g1 = nfg[dcol + 64], g2 = nfg[dcol + 128], g3 = nfg[dcol + 192];
    float c0 = nfb[dcol], c1 = nfb[dcol + 64], c2 = nfb[dcol + 128], c3 = nfb[dcol + 192];
    for (int jj = 0; jj < 8; ++jj) {
      int lo = j8 + jj;
      float v0 = s_a[dcol * 36 + lo];
      float v1 = s_a[(dcol + 64) * 36 + lo];
      float v2 = s_a[(dcol + 128) * 36 + lo];
      float v3 = s_a[(dcol + 192) * 36 + lo];
      float s1 = v0 + v1 + v2 + v3;
      float s2 = v0 * v0 + v1 * v1 + v2 * v2 + v3 * v3;
      #pragma unroll
      for (int off = 1; off < 64; off <<= 1) {
        s1 += __shfl_xor(s1, off);
        s2 += __shfl_xor(s2, off);
      }
      float mu2 = s1 * (1.f / D);
      float var2 = s2 * (1.f / D) - mu2 * mu2;
      float rstd2 = rsqrtf(var2 + 1e-5f);
      s_a[dcol * 36 + lo]         = (v0 - mu2) * rstd2 * g0 + c0;
      s_a[(dcol + 64) * 36 + lo]  = (v1 - mu2) * rstd2 * g1 + c1;
      s_a[(dcol + 128) * 36 + lo] = (v2 - mu2) * rstd2 * g2 + c2;
      s_a[(dcol + 192) * 36 + lo] = (v3 - mu2) * rstd2 * g3 + c3;
    }
  }
  // MLP W1 loop: a-operand = 2 wave-uniform b128 per k from aT
  float4 acc[8];
  #pragma unroll
  for (int jj = 0; jj < 8; ++jj) acc[jj] = make_float4(0.f, 0.f, 0.f, 0.f);
  for (int kb = 0; kb < 256; kb += 32) {
    __syncthreads();  // prior tile reads done (first: LN2 writes visible)
    {
      const float4* wsrc = (const float4*)(W1 + kb * D);
      float4* wdst = (float4*)s_w;
      for (int i = t; i < 2048; i += 256) wdst[i] = wsrc[i];
    }
    __syncthreads();
    #pragma unroll 8
    for (int k = 0; k < 32; ++k) {
      float4 w = *(float4*)&s_w[k * D + d4];
      float4 alo = *(float4*)&s_a[(kb + k) * 36 + j8];      // b128 broadcast
      float4 ahi = *(float4*)&s_a[(kb + k) * 36 + j8 + 4];  // b128 broadcast
      FMA4(alo.x, 0) FMA4(alo.y, 1) FMA4(alo.z, 2) FMA4(alo.w, 3)
      FMA4(ahi.x, 4) FMA4(ahi.y, 5) FMA4(ahi.z, 6) FMA4(ahi.w, 7)
    }
  }
  float4 b1v = *(const float4*)&b1[d4];
  __syncthreads();  // all aT reads done before z overwrites the region
  #pragma unroll
  for (int jj = 0; jj < 8; ++jj) {
    float4 v = acc[jj];
    v.x = gelu_exact(v.x + b1v.x);
    v.y = gelu_exact(v.y + b1v.y);
    v.z = gelu_exact(v.z + b1v.z);
    v.w = gelu_exact(v.w + b1v.w);
    *(float4*)&s_a[(j8 + jj) * 260 + d4] = v;  // z, row-major pitch 260
  }
  {
    const float4* w2s = (const float4*)W2;
    float4* wdst = (float4*)s_w;
    for (int i = t; i < 2048; i += 256) wdst[i] = w2s[i];
  }
  __syncthreads();
  int j = t >> 3, p4 = (t & 7) * 4;
  float4 o = make_float4(0.f, 0.f, 0.f, 0.f);
  for (int dd = 0; dd < 256; ++dd) {
    float zv = s_a[j * 260 + dd];
    float4 w = *(float4*)&s_w[dd * 32 + p4];
    o.x = fmaf(zv, w.x, o.x);
    o.y = fmaf(zv, w.y, o.y);
    o.z = fmaf(zv, w.z, o.z);
    o.w = fmaf(zv, w.w, o.w);
  }
  float4 b2v = *(const float4*)&b2[p4];
  o.x += b2v.x; o.y += b2v.y; o.z += b2v.z; o.w += b2v.w;
  *(float4*)&out[(size_t)(tok0 + j) * 32 + p4] = o;
}

extern "C" void kernel_launch(void* const* d_in, const int* in_sizes, int n_in,
                              void* d_out, int out_size, void* d_ws, size_t ws_size,
                              hipStream_t stream) {
  const float* y    = (const float*)d_in[0];
  const float* Win  = (const float*)d_in[1];
  const float* bin_ = (const float*)d_in[2];
  const float* ng   = (const float*)d_in[3];
  const float* nb   = (const float*)d_in[4];
  const float* A    = (const float*)d_in[5];
  const float* WB   = (const float*)d_in[6];
  const float* WC   = (const float*)d_in[7];
  const float* qd   = (const float*)d_in[8];
  const float* pd   = (const float*)d_in[9];
  const float* nfg  = (const float*)d_in[10];
  const float* nfb  = (const float*)d_in[11];
  const float* W1   = (const float*)d_in[12];
  const float* b1   = (const float*)d_in[13];
  const float* W2   = (const float*)d_in[14];
  const float* b2   = (const float*)d_in[15];

  float* ws = (float*)d_ws;
  float* hnbuf = ws;                          // NTOK*D
  float* delta = ws + 4194304;                // NTOK
  float* Bm    = delta + NTOK;                // NTOK*NX
  float* Cm    = Bm + NTOK * NX;              // NTOK*NX
  float* muv   = Cm + NTOK * NX;              // NTOK
  float* irsv  = muv + NTOK;                  // NTOK
  float* Tbuf  = irsv + NTOK;                 // 512
  float* At    = Tbuf + NBATCH * NCH;         // 4096
  float* Wbct  = At + D * NX;                 // 8192
  float* EX    = Wbct + D * 32;               // 512*4096 = 2M floats

  k0_prep<<<48, 256, 0, stream>>>(A, WB, WC, At, Wbct);
  k1a_front_scan<<<NTOK / 32, 256, 0, stream>>>(y, Win, bin_, ng, nb, Wbct,
                                                qd, pd, At, hnbuf, delta, Bm,
                                                Cm, muv, irsv, EX, Tbuf);
  k2b_chunkscan<<<NBATCH * 16, 256, 0, stream>>>(At, Tbuf, EX);
  k2cd_scan_mlp<<<NTOK / 32, 256, 0, stream>>>(hnbuf, delta, Bm, Cm, At, EX,
                                               muv, irsv, ng, nb, nfg, nfb,
                                               W1, b1, W2, b2, (float*)d_out);
}